// Round 20
// baseline (40.632 us; speedup 1.0000x reference)
//
#include <hip/hip_runtime.h>
#include <math.h>

// PersistenceLoss: BCE(y_true, y_pred) + 0.005 * topo
// topo: per 64x64 patch sort both tensors' values, mean squared diff of
// aligned order statistics. B=64, H=W=512 -> 4096 patches of 4096 elems.
//
// COUNTING-SORT + EVENT-HISTOGRAM, TWO PATCHES PER BLOCK (phase-interleaved):
//   Quantize to NB=256 uniform bins (monotone; topo abs err ~4e-7 << 2e-2).
//   One 256-thread block handles patches {2b, 2b+1}; every phase runs both
//   patches' independent dataflow back-to-back between the same barriers:
//   per-patch barrier cost halves, ILP doubles (R16-R19 plateau showed the
//   critical path is phase latency, not pipe throughput).
//     1. LDS histograms (atomics); both E arrays zeroed in same pass
//     2. packed block-scan (1 bin/thread/patch) -> CDFs in registers
//     3. scatter events E[CA]+=1, E[CB]-=1
//     4. block-scan of E -> D(r); topo += D(r)^2   (both patches)
//   BCE and sq are patch-additive -> one partials entry per block.
//   Two-kernel finish (R12 lesson: device-atomic finish serializes ~150us).

#define THREADS 256
#define NB 256
#define PATCH_N 4096
#define NPART 2048           // blocks = patch pairs

typedef unsigned int u32;

__global__ __launch_bounds__(THREADS) void patch_hist_kernel(
    const float* __restrict__ y_true,
    const float* __restrict__ y_pred,
    float2* __restrict__ partials)
{
    // [HA0(256) | HB0(256) | HA1(256) | HB1(256)]
    __shared__ int SH[4 * NB];
    __shared__ int E0[4100];
    __shared__ int E1[4100];
    __shared__ u32 wsum[8];          // [0..3]=patch0, [4..7]=patch1
    __shared__ int wsumE[8];
    __shared__ float rsum[8];

    const int t = threadIdx.x;
    const int lane = t & 63;
    const int wid  = t >> 6;         // 0..3

    const int bp0 = blockIdx.x * 2;
    const int bp1 = bp0 + 1;
    auto patch_base = [](int bp) -> size_t {
        int bb = bp >> 6, p = bp & 63;
        return (size_t)bb * (512 * 512) + (size_t)(p >> 3) * (64 * 512)
             + (size_t)(p & 7) * 64;
    };
    const size_t base0 = patch_base(bp0);
    const size_t base1 = patch_base(bp1);

    // ---- zero hists (1024 ints) + both E arrays (8192+ ints) ----
    {
        int4 z = make_int4(0, 0, 0, 0);
        reinterpret_cast<int4*>(SH)[t] = z;                // 1024 ints
        reinterpret_cast<int4*>(E0)[t] = z;
        reinterpret_cast<int4*>(E0)[t + 256] = z;
        reinterpret_cast<int4*>(E0)[t + 512] = z;
        reinterpret_cast<int4*>(E0)[t + 768] = z;          // 4096 ints
        reinterpret_cast<int4*>(E1)[t] = z;
        reinterpret_cast<int4*>(E1)[t + 256] = z;
        reinterpret_cast<int4*>(E1)[t + 512] = z;
        reinterpret_cast<int4*>(E1)[t + 768] = z;
        if (t == 0) { E0[4096] = 0; E1[4096] = 0; }
    }
    __syncthreads();

    // ---- load 16 elems/thread/patch: fused BCE + histograms ----
    const size_t ro = (size_t)(t >> 2) * 512 + (size_t)(t & 3) * 16;
    float bce = 0.0f;
    #pragma unroll
    for (int q = 0; q < 4; ++q) {
        float4 va0 = *reinterpret_cast<const float4*>(y_true + base0 + ro + q * 4);
        float4 vb0 = *reinterpret_cast<const float4*>(y_pred + base0 + ro + q * 4);
        float4 va1 = *reinterpret_cast<const float4*>(y_true + base1 + ro + q * 4);
        float4 vb1 = *reinterpret_cast<const float4*>(y_pred + base1 + ro + q * 4);
        float ya0[4] = {va0.x, va0.y, va0.z, va0.w};
        float yb0[4] = {vb0.x, vb0.y, vb0.z, vb0.w};
        float ya1[4] = {va1.x, va1.y, va1.z, va1.w};
        float yb1[4] = {vb1.x, vb1.y, vb1.z, vb1.w};
        #pragma unroll
        for (int i = 0; i < 4; ++i) {
            // patch 0
            {
                float yt = ya0[i], yp = yb0[i];
                float pcl = fminf(fmaxf(yp, 1e-7f), 1.0f - 1e-7f);
                float L1 = __logf(pcl), L0 = __logf(1.0f - pcl);
                bce -= L0 + yt * (L1 - L0);
                unsigned ba = min((unsigned)(yt * (float)NB), NB - 1u);
                unsigned bn = min((unsigned)(yp * (float)NB), NB - 1u);
                atomicAdd(&SH[ba], 1);
                atomicAdd(&SH[NB + bn], 1);
            }
            // patch 1
            {
                float yt = ya1[i], yp = yb1[i];
                float pcl = fminf(fmaxf(yp, 1e-7f), 1.0f - 1e-7f);
                float L1 = __logf(pcl), L0 = __logf(1.0f - pcl);
                bce -= L0 + yt * (L1 - L0);
                unsigned ba = min((unsigned)(yt * (float)NB), NB - 1u);
                unsigned bn = min((unsigned)(yp * (float)NB), NB - 1u);
                atomicAdd(&SH[2 * NB + ba], 1);
                atomicAdd(&SH[3 * NB + bn], 1);
            }
        }
    }
    __syncthreads();

    // ---- packed CDF scans (interleaved, 1 bin/thread/patch) ----
    const u32 v0 = ((u32)SH[t] << 16)          | (u32)SH[NB + t];
    const u32 v1 = ((u32)SH[2 * NB + t] << 16) | (u32)SH[3 * NB + t];
    u32 ss0 = v0, ss1 = v1;
    #pragma unroll
    for (int off = 1; off < 64; off <<= 1) {
        u32 x0 = __shfl_up(ss0, off, 64);
        u32 x1 = __shfl_up(ss1, off, 64);
        if (lane >= off) { ss0 += x0; ss1 += x1; }
    }
    if (lane == 63) { wsum[wid] = ss0; wsum[4 + wid] = ss1; }
    __syncthreads();
    u32 wb0 = 0, wb1 = 0;
    #pragma unroll
    for (int w = 0; w < 3; ++w) {
        if (wid > w) { wb0 += wsum[w]; wb1 += wsum[4 + w]; }
    }
    const u32 cdf0 = wb0 + ss0;
    const u32 cdf1 = wb1 + ss1;

    // ---- scatter events ----
    atomicAdd(&E0[cdf0 >> 16], 1);
    atomicAdd(&E0[cdf0 & 0xFFFFu], -1);
    atomicAdd(&E1[cdf1 >> 16], 1);
    atomicAdd(&E1[cdf1 & 0xFFFFu], -1);
    __syncthreads();

    // ---- inclusive scans of E0,E1; topo += D(r)^2 ----
    int el0[16], el1[16];
    {
        const int4* p0 = reinterpret_cast<const int4*>(E0 + t * 16);
        const int4* p1 = reinterpret_cast<const int4*>(E1 + t * 16);
        #pragma unroll
        for (int q = 0; q < 4; ++q) {
            int4 a = p0[q], b = p1[q];
            el0[q*4+0]=a.x; el0[q*4+1]=a.y; el0[q*4+2]=a.z; el0[q*4+3]=a.w;
            el1[q*4+0]=b.x; el1[q*4+1]=b.y; el1[q*4+2]=b.z; el1[q*4+3]=b.w;
        }
    }
    int es0 = 0, es1 = 0;
    #pragma unroll
    for (int k = 0; k < 16; ++k) {
        es0 += el0[k]; el0[k] = es0;
        es1 += el1[k]; el1[k] = es1;
    }
    int ess0 = es0, ess1 = es1;
    #pragma unroll
    for (int off = 1; off < 64; off <<= 1) {
        int x0 = __shfl_up(ess0, off, 64);
        int x1 = __shfl_up(ess1, off, 64);
        if (lane >= off) { ess0 += x0; ess1 += x1; }
    }
    if (lane == 63) { wsumE[wid] = ess0; wsumE[4 + wid] = ess1; }
    __syncthreads();
    int ewb0 = 0, ewb1 = 0;
    #pragma unroll
    for (int w = 0; w < 3; ++w) {
        if (wid > w) { ewb0 += wsumE[w]; ewb1 += wsumE[4 + w]; }
    }
    const int eb0 = ewb0 + ess0 - es0;
    const int eb1 = ewb1 + ess1 - es1;
    float sq = 0.0f;
    #pragma unroll
    for (int k = 0; k < 16; ++k) {
        float d0 = (float)(eb0 + el0[k]);
        float d1 = (float)(eb1 + el1[k]);
        sq = fmaf(d0, d0, sq);
        sq = fmaf(d1, d1, sq);
    }

    // ---- block reduction (bce, sq are sums over both patches) ----
    #pragma unroll
    for (int off = 32; off >= 1; off >>= 1) {
        bce += __shfl_down(bce, off, 64);
        sq  += __shfl_down(sq, off, 64);
    }
    if (lane == 0) { rsum[wid] = bce; rsum[4 + wid] = sq; }
    __syncthreads();
    if (t == 0) {
        const float inv_nb2 = 1.0f / ((float)NB * (float)NB);
        partials[blockIdx.x] =
            make_float2(rsum[0] + rsum[1] + rsum[2] + rsum[3],
                        (rsum[4] + rsum[5] + rsum[6] + rsum[7]) * inv_nb2);
    }
}

__global__ __launch_bounds__(256) void final_reduce_kernel(
    const float2* __restrict__ partials,
    float* __restrict__ out)
{
    __shared__ float rb[256];
    __shared__ float rs[256];
    const int tid = threadIdx.x;
    float bsum = 0.0f, ssum = 0.0f;
    for (int i = tid; i < NPART; i += 256) {
        float2 v = partials[i];
        bsum += v.x;
        ssum += v.y;
    }
    rb[tid] = bsum;
    rs[tid] = ssum;
    __syncthreads();
    for (int off = 128; off > 0; off >>= 1) {
        if (tid < off) {
            rb[tid] += rb[tid + off];
            rs[tid] += rs[tid + off];
        }
        __syncthreads();
    }
    if (tid == 0) {
        // BCE mean and topo mean share denominator 64*512*512 = 16777216
        out[0] = (rb[0] + 0.005f * rs[0]) * (1.0f / 16777216.0f);
    }
}

extern "C" void kernel_launch(void* const* d_in, const int* in_sizes, int n_in,
                              void* d_out, int out_size, void* d_ws, size_t ws_size,
                              hipStream_t stream) {
    const float* y_true = (const float*)d_in[0];
    const float* y_pred = (const float*)d_in[1];
    float* out = (float*)d_out;
    float2* partials = (float2*)d_ws;   // 2048 * 8 B = 16 KB

    hipLaunchKernelGGL(patch_hist_kernel, dim3(NPART), dim3(THREADS), 0, stream,
                       y_true, y_pred, partials);
    hipLaunchKernelGGL(final_reduce_kernel, dim3(1), dim3(256), 0, stream,
                       partials, out);
}

// Round 21
// 36.627 us; speedup vs baseline: 1.1093x; 1.1093x over previous
//
#include <hip/hip_runtime.h>
#include <math.h>

// PersistenceLoss: BCE(y_true, y_pred) + 0.005 * topo
// topo: per 64x64 patch sort both tensors' values, mean squared diff of
// aligned order statistics. B=64, H=W=512 -> 4096 patches of 4096 elems.
//
// COUNTING-SORT + EVENT-HISTOGRAM (no sorts, no dependent walks):
//   Quantize to NB=256 uniform bins (monotone; topo abs err ~4e-7 << 2e-2).
//   Per patch, one 256-THREAD block (4 waves) x 16 elems/thread:
//   LDS ~18.8KB -> 8 blocks/CU at the 32-wave cap (measured optimum across
//   R14-R20: {512t,25KB} and {256t,19KB} tie; 1024t/2-patch variants regress
//   — the kernel is phase-latency-bound and lives on resident-wave TLP).
//     1. LDS histograms HA,HB (atomics); E zeroed in same initial pass
//     2. packed block-scan, EXACTLY 1 bin/thread -> inclusive CDFs in regs
//     3. scatter events E[CA]+=1, E[CB]-=1 (disjoint array, no extra bar)
//     4. block-scan of E (16 ranks/thread) -> D(r); topo = sum D(r)^2
//   Identity: QA(r) = #{a : CA(a) <= r} = prefix_sum(events)(r).
//   BCE fused into load. Two-kernel finish (R12 lesson: same-address device
//   atomics + fence serialize cross-XCD ~150us; a 2nd launch is cheaper).

#define THREADS 256
#define NB 256
#define PATCH_N 4096
#define NBLOCKS 4096

typedef unsigned int u32;

__global__ __launch_bounds__(THREADS) void patch_hist_kernel(
    const float* __restrict__ y_true,
    const float* __restrict__ y_pred,
    float2* __restrict__ partials)
{
    __shared__ int SH[2 * NB];      // HA = SH[0..NB), HB = SH[NB..2NB)
    __shared__ int E[4100];         // event array over ranks 0..4096
    __shared__ u32 wsum[4];         // packed per-wave totals (A<<16 | B)
    __shared__ int wsumE[4];
    __shared__ float rsum[8];

    const int bp = blockIdx.x;       // patch id 0..4095
    const int bb = bp >> 6;          // batch index
    const int p  = bp & 63;          // patch within image
    const int pr = p >> 3;
    const int pc = p & 7;
    const size_t base = (size_t)bb * (512 * 512)
                      + (size_t)pr * (64 * 512)
                      + (size_t)pc * 64;
    const int t = threadIdx.x;
    const int lane = t & 63;
    const int wid  = t >> 6;         // 0..3

    // ---- zero hist (512 ints) + event (4096+ ints) arrays ----
    {
        int4 z = make_int4(0, 0, 0, 0);
        if (t < 128) reinterpret_cast<int4*>(SH)[t] = z;   // 512 ints
        reinterpret_cast<int4*>(E)[t] = z;                 // 1024 ints
        reinterpret_cast<int4*>(E)[t + 256] = z;
        reinterpret_cast<int4*>(E)[t + 512] = z;
        reinterpret_cast<int4*>(E)[t + 768] = z;           // 4096 ints
        if (t == 0) E[4096] = 0;
    }
    __syncthreads();

    // ---- load 16 elems/thread: fused BCE + histogram build ----
    // 4 threads per 64-float row: row = t>>2, col = (t&3)*16
    const size_t rowbase = base + (size_t)(t >> 2) * 512 + (size_t)(t & 3) * 16;
    float bce = 0.0f;
    #pragma unroll
    for (int q = 0; q < 4; ++q) {
        float4 va = *reinterpret_cast<const float4*>(y_true + rowbase + q * 4);
        float4 vb = *reinterpret_cast<const float4*>(y_pred + rowbase + q * 4);
        float ya[4] = {va.x, va.y, va.z, va.w};
        float yb[4] = {vb.x, vb.y, vb.z, vb.w};
        #pragma unroll
        for (int i = 0; i < 4; ++i) {
            float yt = ya[i], yp = yb[i];
            float pcl = fminf(fmaxf(yp, 1e-7f), 1.0f - 1e-7f);
            // log1pf(-p) == logf(1-p): Sterbenz-exact for p>=0.5; __logf =
            // v_log_f32 + mul. BCE abs err ~1e-6 << threshold.
            float L1 = __logf(pcl);
            float L0 = __logf(1.0f - pcl);
            bce -= L0 + yt * (L1 - L0);
            // v_cvt_u32_f32 saturates negatives to 0; values < 1 so *NB < NB
            unsigned ba = min((unsigned)(yt * (float)NB), NB - 1u);
            unsigned bn = min((unsigned)(yp * (float)NB), NB - 1u);
            atomicAdd(&SH[ba], 1);
            atomicAdd(&SH[NB + bn], 1);
        }
    }
    __syncthreads();

    // ---- packed CDF scan: thread t owns bin t of both hists ----
    // packed value = (A << 16) | B; partial sums <= 4096 -> no carry.
    const u32 v = ((u32)SH[t] << 16) | (u32)SH[NB + t];
    u32 ss = v;
    #pragma unroll
    for (int off = 1; off < 64; off <<= 1) {
        u32 x = __shfl_up(ss, off, 64);
        if (lane >= off) ss += x;
    }
    if (lane == 63) wsum[wid] = ss;
    __syncthreads();
    u32 wb = 0;
    #pragma unroll
    for (int w = 0; w < 3; ++w)
        if (wid > w) wb += wsum[w];
    const u32 cdf = wb + ss;          // inclusive packed CDF at bin t

    // ---- scatter events (E disjoint from SH: no barrier needed) ----
    atomicAdd(&E[cdf >> 16], 1);
    atomicAdd(&E[cdf & 0xFFFFu], -1);
    __syncthreads();

    // ---- inclusive scan of E over r=0..4095; topo += D(r)^2 ----
    // thread t owns r in [t*16, t*16+16)
    int el[16];
    {
        const int4* ep = reinterpret_cast<const int4*>(E + t * 16);
        int4 e0 = ep[0], e1 = ep[1], e2 = ep[2], e3 = ep[3];
        el[0]=e0.x;  el[1]=e0.y;  el[2]=e0.z;  el[3]=e0.w;
        el[4]=e1.x;  el[5]=e1.y;  el[6]=e1.z;  el[7]=e1.w;
        el[8]=e2.x;  el[9]=e2.y;  el[10]=e2.z; el[11]=e2.w;
        el[12]=e3.x; el[13]=e3.y; el[14]=e3.z; el[15]=e3.w;
    }
    int es = 0;
    #pragma unroll
    for (int k = 0; k < 16; ++k) {
        es += el[k];
        el[k] = es;          // local inclusive
    }
    int ess = es;
    #pragma unroll
    for (int off = 1; off < 64; off <<= 1) {
        int x = __shfl_up(ess, off, 64);
        if (lane >= off) ess += x;
    }
    if (lane == 63) wsumE[wid] = ess;
    __syncthreads();
    int ewb = 0;
    #pragma unroll
    for (int w = 0; w < 3; ++w)
        if (wid > w) ewb += wsumE[w];
    const int ebase = ewb + ess - es;    // exclusive base
    float sq = 0.0f;
    #pragma unroll
    for (int k = 0; k < 16; ++k) {
        float d = (float)(ebase + el[k]);   // D(r) in bin units
        sq = fmaf(d, d, sq);
    }

    // ---- block reduction ----
    #pragma unroll
    for (int off = 32; off >= 1; off >>= 1) {
        bce += __shfl_down(bce, off, 64);
        sq  += __shfl_down(sq, off, 64);
    }
    if (lane == 0) { rsum[wid] = bce; rsum[4 + wid] = sq; }
    __syncthreads();
    if (t == 0) {
        const float inv_nb2 = 1.0f / ((float)NB * (float)NB);
        partials[bp] = make_float2(rsum[0] + rsum[1] + rsum[2] + rsum[3],
                                   (rsum[4] + rsum[5] + rsum[6] + rsum[7]) * inv_nb2);
    }
}

__global__ __launch_bounds__(256) void final_reduce_kernel(
    const float2* __restrict__ partials,
    float* __restrict__ out)
{
    __shared__ float rb[256];
    __shared__ float rs[256];
    const int tid = threadIdx.x;
    float bsum = 0.0f, ssum = 0.0f;
    for (int i = tid; i < NBLOCKS; i += 256) {
        float2 v = partials[i];
        bsum += v.x;
        ssum += v.y;
    }
    rb[tid] = bsum;
    rs[tid] = ssum;
    __syncthreads();
    for (int off = 128; off > 0; off >>= 1) {
        if (tid < off) {
            rb[tid] += rb[tid + off];
            rs[tid] += rs[tid + off];
        }
        __syncthreads();
    }
    if (tid == 0) {
        // BCE mean and topo mean share denominator 64*512*512 = 16777216
        out[0] = (rb[0] + 0.005f * rs[0]) * (1.0f / 16777216.0f);
    }
}

extern "C" void kernel_launch(void* const* d_in, const int* in_sizes, int n_in,
                              void* d_out, int out_size, void* d_ws, size_t ws_size,
                              hipStream_t stream) {
    const float* y_true = (const float*)d_in[0];
    const float* y_pred = (const float*)d_in[1];
    float* out = (float*)d_out;
    float2* partials = (float2*)d_ws;   // 4096 * 8 B = 32 KB

    hipLaunchKernelGGL(patch_hist_kernel, dim3(NBLOCKS), dim3(THREADS), 0, stream,
                       y_true, y_pred, partials);
    hipLaunchKernelGGL(final_reduce_kernel, dim3(1), dim3(256), 0, stream,
                       partials, out);
}